// Round 1
// baseline (779.396 us; speedup 1.0000x reference)
//
#include <hip/hip_runtime.h>

// Pairwise interaction: out[b, p, e] = in[b, I[p], e] * in[b, J[p], e]
// B=4096, F=39, E=64, P = F*(F-1)/2 = 741 (strict upper triangle, row-major).
//
// Register-resident variant: each thread owns one embedding lane e (t&63) and
// keeps all 39 field values for that lane in registers. Pair indices are
// compile-time (constexpr table + full unroll, wave-uniform range selection),
// so there is NO LDS, no __syncthreads, no per-iteration table load, and no
// runtime register indexing (which would spill to scratch). Inner loop is
// v_mul_f32 + global_store_dword only. Each wave store = 256 B contiguous
// (4 full 64 B lines), so write coalescing is preserved.

#define NF 39
#define NE 64
#define NP 741
#define NB 4096

struct Tab {
    unsigned char pi[NP];
    unsigned char pj[NP];
};
constexpr Tab make_tab() {
    Tab t{};
    int p = 0;
    for (int i = 0; i < NF; ++i)
        for (int j = i + 1; j < NF; ++j) {
            t.pi[p] = (unsigned char)i;
            t.pj[p] = (unsigned char)j;
            ++p;
        }
    return t;
}
constexpr Tab TAB = make_tab();

// Emit pairs [BASE, BASE+CNT). BASE/CNT are template params and the loop is
// fully unrolled, so TAB.pi[p] / TAB.pj[p] fold to compile-time constants and
// r[...] is statically indexed (stays in VGPRs — rule #20).
template <int BASE, int CNT>
__device__ __forceinline__ void emit_pairs(const float (&r)[NF],
                                           float* __restrict__ outp) {
#pragma unroll
    for (int k = 0; k < CNT; ++k) {
        const int p = BASE + k;
        outp[p * NE] = r[TAB.pi[p]] * r[TAB.pj[p]];
    }
}

__global__ __launch_bounds__(256) void pairwise_kernel(
        const float* __restrict__ in, float* __restrict__ out) {
    const int b = blockIdx.x;
    const int t = threadIdx.x;
    const int e = t & 63;   // embedding lane owned by this thread
    const int w = t >> 6;   // wave id 0..3 — wave-uniform

    // Load this batch row's column e into registers: 39 coalesced dword loads
    // (each wave reads 256 B contiguous per field; waves 1-3 hit L1).
    const float* __restrict__ inb = in + (size_t)b * (NF * NE) + e;
    float r[NF];
#pragma unroll
    for (int f = 0; f < NF; ++f) r[f] = inb[f * NE];

    float* __restrict__ outp = out + (size_t)b * (NP * NE) + e;

    // 741 = 186 + 185 + 185 + 185. Wave-uniform switch: no divergence,
    // each wave runs its own fully-unrolled pair range.
    switch (w) {
        case 0:  emit_pairs<0,   186>(r, outp); break;
        case 1:  emit_pairs<186, 185>(r, outp); break;
        case 2:  emit_pairs<371, 185>(r, outp); break;
        default: emit_pairs<556, 185>(r, outp); break;
    }
}

extern "C" void kernel_launch(void* const* d_in, const int* in_sizes, int n_in,
                              void* d_out, int out_size, void* d_ws, size_t ws_size,
                              hipStream_t stream) {
    const float* in = (const float*)d_in[0];
    float* out = (float*)d_out;
    pairwise_kernel<<<dim3(NB), dim3(256), 0, stream>>>(in, out);
}